// Round 3
// baseline (160.249 us; speedup 1.0000x reference)
//
#include <hip/hip_runtime.h>

namespace {

constexpr int B  = 4;
constexpr int V  = 5000;
constexpr int NF = 10000;
constexpr int H  = 512;
constexpr int W  = 512;
constexpr int HW = H * W;          // 2^18
constexpr int NPIX = B * HW;

// output float offsets
constexpr int OFF_IMAGES  = 0;
constexpr int OFF_ALBEDO  = 3 * NPIX;
constexpr int OFF_ALPHA   = OFF_ALBEDO + 3 * NPIX;
constexpr int OFF_POSMASK = OFF_ALPHA + NPIX;
constexpr int OFF_SHADING = OFF_POSMASK + NPIX;
constexpr int OFF_GRID    = OFF_SHADING + 3 * NPIX;
constexpr int OFF_NORMALS = OFF_GRID + 2 * NPIX;

// SH constants
constexpr float C0 = 0.28209479177387814f;
constexpr float C1 = 1.0233267079464885f;
constexpr float C4 = 0.8580855308097834f;
constexpr float C7 = 0.42904276540489156f;
constexpr float C8 = 0.24770795610037571f;

__global__ void zero_int_k(int* __restrict__ p, int n) {
    int i = blockIdx.x * blockDim.x + threadIdx.x;
    if (i < n) p[i] = 0;
}

__global__ void count_k(const int* __restrict__ faces, int* __restrict__ counts) {
    int f = blockIdx.x * blockDim.x + threadIdx.x;
    if (f >= NF) return;
    atomicAdd(&counts[faces[f*3+0]], 1);
    atomicAdd(&counts[faces[f*3+1]], 1);
    atomicAdd(&counts[faces[f*3+2]], 1);
}

// single block, 256 threads: exclusive scan of counts[V] -> offsets[V+1], cursor[V]
__global__ __launch_bounds__(256) void scan_k(const int* __restrict__ counts,
                                              int* __restrict__ offsets,
                                              int* __restrict__ cursor) {
    __shared__ int part[256];
    constexpr int CHUNK = (V + 255) / 256;   // 20
    int t = threadIdx.x;
    int i0 = t * CHUNK;
    int s = 0;
    for (int j = 0; j < CHUNK; ++j) { int i = i0 + j; if (i < V) s += counts[i]; }
    part[t] = s;
    __syncthreads();
    for (int d = 1; d < 256; d <<= 1) {
        int v = (t >= d) ? part[t - d] : 0;
        __syncthreads();
        part[t] += v;
        __syncthreads();
    }
    int base = (t == 0) ? 0 : part[t - 1];
    for (int j = 0; j < CHUNK; ++j) {
        int i = i0 + j;
        if (i < V) { offsets[i] = base; cursor[i] = base; base += counts[i]; }
    }
    if (t == 255) offsets[V] = base;
}

// fill adjacency: key = phase*NF + f; phase 0 = slot1, 1 = slot2, 2 = slot0 (ref order)
__global__ void fill_k(const int* __restrict__ faces, int* __restrict__ cursor,
                       int* __restrict__ keys) {
    int f = blockIdx.x * blockDim.x + threadIdx.x;
    if (f >= NF) return;
    int i0 = faces[f*3+0], i1 = faces[f*3+1], i2 = faces[f*3+2];
    int p;
    p = atomicAdd(&cursor[i1], 1); keys[p] = 0*NF + f;
    p = atomicAdd(&cursor[i2], 1); keys[p] = 1*NF + f;
    p = atomicAdd(&cursor[i0], 1); keys[p] = 2*NF + f;
}

// deterministic per-vertex order: insertion sort (keys unique per vertex)
__global__ void sort_k(const int* __restrict__ offsets, int* __restrict__ keys) {
    int v = blockIdx.x * blockDim.x + threadIdx.x;
    if (v >= V) return;
    int lo = offsets[v], hi = offsets[v+1];
    for (int i = lo + 1; i < hi; ++i) {
        int k = keys[i];
        int j = i - 1;
        while (j >= lo && keys[j] > k) { keys[j+1] = keys[j]; --j; }
        keys[j+1] = k;
    }
}

// per (b,v): accumulate face normals in exact reference order, normalize, write
__global__ void accum_k(const int* __restrict__ offsets, const int* __restrict__ keys,
                        const int* __restrict__ faces,
                        const float* __restrict__ verts, const float* __restrict__ tverts,
                        float* __restrict__ normV, float* __restrict__ normT) {
    int i = blockIdx.x * blockDim.x + threadIdx.x;
    if (i >= B * V) return;
    int b = i / V, v = i - b * V;
    const float* vb = verts  + (size_t)b * V * 3;
    const float* tb = tverts + (size_t)b * V * 3;
    float nx = 0, ny = 0, nz = 0, tx = 0, ty = 0, tz = 0;
    int lo = offsets[v], hi = offsets[v+1];
    for (int e = lo; e < hi; ++e) {
        int key = keys[e];
        int phase = key / NF;
        int f = key - phase * NF;
        int j0 = faces[f*3+0], j1 = faces[f*3+1], j2 = faces[f*3+2];
        // geometric normals
        {
            float x0 = vb[j0*3], y0 = vb[j0*3+1], z0 = vb[j0*3+2];
            float x1 = vb[j1*3], y1 = vb[j1*3+1], z1 = vb[j1*3+2];
            float x2 = vb[j2*3], y2 = vb[j2*3+1], z2 = vb[j2*3+2];
            float ax, ay, az, bx, by, bz;
            if (phase == 0)      { ax=x2-x1; ay=y2-y1; az=z2-z1; bx=x0-x1; by=y0-y1; bz=z0-z1; }
            else if (phase == 1) { ax=x0-x2; ay=y0-y2; az=z0-z2; bx=x1-x2; by=y1-y2; bz=z1-z2; }
            else                 { ax=x1-x0; ay=y1-y0; az=z1-z0; bx=x2-x0; by=y2-y0; bz=z2-z0; }
            nx += ay*bz - az*by;
            ny += az*bx - ax*bz;
            nz += ax*by - ay*bx;
        }
        // transformed normals (z += 10 before edges, matching ref rounding)
        {
            float x0 = tb[j0*3], y0 = tb[j0*3+1], z0 = tb[j0*3+2] + 10.0f;
            float x1 = tb[j1*3], y1 = tb[j1*3+1], z1 = tb[j1*3+2] + 10.0f;
            float x2 = tb[j2*3], y2 = tb[j2*3+1], z2 = tb[j2*3+2] + 10.0f;
            float ax, ay, az, bx, by, bz;
            if (phase == 0)      { ax=x2-x1; ay=y2-y1; az=z2-z1; bx=x0-x1; by=y0-y1; bz=z0-z1; }
            else if (phase == 1) { ax=x0-x2; ay=y0-y2; az=z0-z2; bx=x1-x2; by=y1-y2; bz=z1-z2; }
            else                 { ax=x1-x0; ay=y1-y0; az=z1-z0; bx=x2-x0; by=y2-y0; bz=z2-z0; }
            tx += ay*bz - az*by;
            ty += az*bx - ax*bz;
            tz += ax*by - ay*bx;
        }
    }
    {
        float inv = 1.0f / fmaxf(sqrtf(nx*nx + ny*ny + nz*nz), 1e-6f);
        normV[i*3+0] = nx*inv; normV[i*3+1] = ny*inv; normV[i*3+2] = nz*inv;
    }
    {
        float inv = 1.0f / fmaxf(sqrtf(tx*tx + ty*ty + tz*tz), 1e-6f);
        normT[i*3+0] = tx*inv; normT[i*3+1] = ty*inv; normT[i*3+2] = tz*inv;
    }
}

__global__ __launch_bounds__(256) void pixel_k(
    const int*   __restrict__ ptf,
    const float* __restrict__ bary,
    const int*   __restrict__ faces,
    const float* __restrict__ fuv,
    const float* __restrict__ verts,
    const float* __restrict__ normV,
    const float* __restrict__ normT,
    const float* __restrict__ albedo,
    const float* __restrict__ lights,
    float*       __restrict__ out) {
    int pix = blockIdx.x * 256 + threadIdx.x;
    if (pix >= NPIX) return;
    int b  = pix >> 18;
    int hw = pix & (HW - 1);

    float pv[12];
#pragma unroll
    for (int d = 0; d < 12; ++d) pv[d] = 0.0f;
    float vis = 0.0f;
    int f = ptf[pix];
    if (f >= 0) {
        vis = 1.0f;
        int fb = f / NF;
        int fi = f - fb * NF;
        int vi0 = faces[fi*3+0], vi1 = faces[fi*3+1], vi2 = faces[fi*3+2];
        float wk[3] = {bary[pix*3+0], bary[pix*3+1], bary[pix*3+2]};
        int gv[3] = {fb*V + vi0, fb*V + vi1, fb*V + vi2};
#pragma unroll
        for (int k = 0; k < 3; ++k) {
            float wkk = wk[k];
            const float* uv = fuv + ((size_t)fi*3 + k)*3;
            pv[0] += wkk*uv[0]; pv[1] += wkk*uv[1]; pv[2] += wkk*uv[2];
            int g = gv[k]*3;
            pv[3] += wkk*normT[g+0]; pv[4]  += wkk*normT[g+1]; pv[5]  += wkk*normT[g+2];
            pv[6] += wkk*verts[g+0]; pv[7]  += wkk*verts[g+1]; pv[8]  += wkk*verts[g+2];
            pv[9] += wkk*normV[g+0]; pv[10] += wkk*normV[g+1]; pv[11] += wkk*normV[g+2];
        }
    }

    float nx = pv[9], ny = pv[10], nz = pv[11];
    float shb[9] = {C0, C1*nx, C1*ny, C1*nz, C4*nx*ny, C4*nx*nz, C4*ny*nz,
                    C7*(nx*nx - ny*ny), C8*(3.0f*nz*nz - 1.0f)};
    const float* L = lights + b*27;
    float s0 = 0.0f, s1 = 0.0f, s2 = 0.0f;
#pragma unroll
    for (int k = 0; k < 9; ++k) {
        float sk = shb[k];
        s0 += L[k*3+0]*sk; s1 += L[k*3+1]*sk; s2 += L[k*3+2]*sk;
    }

    float gx = (pv[0] + 1.0f) * 0.5f * (float)W - 0.5f;
    float gy = (pv[1] + 1.0f) * 0.5f * (float)H - 0.5f;
    float x0 = floorf(gx), y0 = floorf(gy);
    float wx1 = gx - x0, wx0 = 1.0f - wx1;
    float wy1 = gy - y0, wy0 = 1.0f - wy1;
    float a0 = 0.0f, a1 = 0.0f, a2 = 0.0f;
    const float* ab = albedo + (size_t)b * 3 * HW;
    {
        float fx[4] = {x0, x0 + 1.0f, x0,        x0 + 1.0f};
        float fy[4] = {y0, y0,        y0 + 1.0f, y0 + 1.0f};
        float wt[4] = {wx0*wy0, wx1*wy0, wx0*wy1, wx1*wy1};
#pragma unroll
        for (int c = 0; c < 4; ++c) {
            bool valid = (fx[c] >= 0.0f) && (fx[c] <= (float)(W-1)) &&
                         (fy[c] >= 0.0f) && (fy[c] <= (float)(H-1));
            if (valid) {
                int ix = (int)fx[c];
                int iy = (int)fy[c];
                int o = iy * W + ix;
                float wgt = wt[c];
                a0 += wgt * ab[o];
                a1 += wgt * ab[HW + o];
                a2 += wgt * ab[2*HW + o];
            }
        }
    }

    int obase = b * 3 * HW + hw;
    out[OFF_IMAGES + obase         ] = a0 * s0 * vis;
    out[OFF_IMAGES + obase +   HW  ] = a1 * s1 * vis;
    out[OFF_IMAGES + obase + 2*HW  ] = a2 * s2 * vis;
    out[OFF_ALBEDO + obase         ] = a0;
    out[OFF_ALBEDO + obase +   HW  ] = a1;
    out[OFF_ALBEDO + obase + 2*HW  ] = a2;
    out[OFF_ALPHA   + pix] = vis;
    out[OFF_POSMASK + pix] = (pv[5] < -0.05f) ? 1.0f : 0.0f;
    out[OFF_SHADING + obase        ] = s0;
    out[OFF_SHADING + obase +   HW ] = s1;
    out[OFF_SHADING + obase + 2*HW ] = s2;
    out[OFF_GRID + pix*2 + 0] = pv[0];
    out[OFF_GRID + pix*2 + 1] = pv[1];
}

} // namespace

extern "C" void kernel_launch(void* const* d_in, const int* in_sizes, int n_in,
                              void* d_out, int out_size, void* d_ws, size_t ws_size,
                              hipStream_t stream) {
    const float* verts  = (const float*)d_in[0];
    const float* tverts = (const float*)d_in[1];
    const float* albedo = (const float*)d_in[2];
    const float* lights = (const float*)d_in[3];
    const float* fuv    = (const float*)d_in[4];
    const float* bary   = (const float*)d_in[5];
    const int*   faces  = (const int*)d_in[6];
    const int*   ptf    = (const int*)d_in[7];
    float* out = (float*)d_out;

    int* counts  = (int*)d_ws;            // V
    int* offsets = counts + V;            // V+1
    int* cursor  = offsets + V + 1;       // V
    int* keys    = cursor + V;            // 3*NF
    float* normT = (float*)(keys + 3*NF); // B*V*3
    float* normV = out + OFF_NORMALS;

    zero_int_k<<<(V + 255)/256, 256, 0, stream>>>(counts, V);
    count_k<<<(NF + 255)/256, 256, 0, stream>>>(faces, counts);
    scan_k<<<1, 256, 0, stream>>>(counts, offsets, cursor);
    fill_k<<<(NF + 255)/256, 256, 0, stream>>>(faces, cursor, keys);
    sort_k<<<(V + 255)/256, 256, 0, stream>>>(offsets, keys);
    accum_k<<<(B*V + 255)/256, 256, 0, stream>>>(offsets, keys, faces, verts, tverts,
                                                 normV, normT);
    pixel_k<<<NPIX/256, 256, 0, stream>>>(ptf, bary, faces, fuv, verts, normV, normT,
                                          albedo, lights, out);
}

// Round 4
// 127.186 us; speedup vs baseline: 1.2600x; 1.2600x over previous
//
#include <hip/hip_runtime.h>

namespace {

constexpr int B  = 4;
constexpr int V  = 5000;
constexpr int NF = 10000;
constexpr int H  = 512;
constexpr int W  = 512;
constexpr int HW = H * W;          // 2^18
constexpr int NPIX = B * HW;

// output float offsets
constexpr int OFF_IMAGES  = 0;
constexpr int OFF_ALBEDO  = 3 * NPIX;
constexpr int OFF_ALPHA   = OFF_ALBEDO + 3 * NPIX;
constexpr int OFF_POSMASK = OFF_ALPHA + NPIX;
constexpr int OFF_SHADING = OFF_POSMASK + NPIX;
constexpr int OFF_GRID    = OFF_SHADING + 3 * NPIX;
constexpr int OFF_NORMALS = OFF_GRID + 2 * NPIX;

// SH constants
constexpr float C0 = 0.28209479177387814f;
constexpr float C1 = 1.0233267079464885f;
constexpr float C4 = 0.8580855308097834f;
constexpr float C7 = 0.42904276540489156f;
constexpr float C8 = 0.24770795610037571f;

__global__ void zero_int_k(int* __restrict__ p, int n) {
    int i = blockIdx.x * blockDim.x + threadIdx.x;
    if (i < n) p[i] = 0;
}

__global__ void count_k(const int* __restrict__ faces, int* __restrict__ counts) {
    int f = blockIdx.x * blockDim.x + threadIdx.x;
    if (f >= NF) return;
    atomicAdd(&counts[faces[f*3+0]], 1);
    atomicAdd(&counts[faces[f*3+1]], 1);
    atomicAdd(&counts[faces[f*3+2]], 1);
}

__global__ __launch_bounds__(256) void scan_k(const int* __restrict__ counts,
                                              int* __restrict__ offsets,
                                              int* __restrict__ cursor) {
    __shared__ int part[256];
    constexpr int CHUNK = (V + 255) / 256;   // 20
    int t = threadIdx.x;
    int i0 = t * CHUNK;
    int s = 0;
    for (int j = 0; j < CHUNK; ++j) { int i = i0 + j; if (i < V) s += counts[i]; }
    part[t] = s;
    __syncthreads();
    for (int d = 1; d < 256; d <<= 1) {
        int v = (t >= d) ? part[t - d] : 0;
        __syncthreads();
        part[t] += v;
        __syncthreads();
    }
    int base = (t == 0) ? 0 : part[t - 1];
    for (int j = 0; j < CHUNK; ++j) {
        int i = i0 + j;
        if (i < V) { offsets[i] = base; cursor[i] = base; base += counts[i]; }
    }
    if (t == 255) offsets[V] = base;
}

// key = phase*NF + f; phase 0 = slot1, 1 = slot2, 2 = slot0 (reference .at order)
__global__ void fill_k(const int* __restrict__ faces, int* __restrict__ cursor,
                       int* __restrict__ keys) {
    int f = blockIdx.x * blockDim.x + threadIdx.x;
    if (f >= NF) return;
    int i0 = faces[f*3+0], i1 = faces[f*3+1], i2 = faces[f*3+2];
    int p;
    p = atomicAdd(&cursor[i1], 1); keys[p] = 0*NF + f;
    p = atomicAdd(&cursor[i2], 1); keys[p] = 1*NF + f;
    p = atomicAdd(&cursor[i0], 1); keys[p] = 2*NF + f;
}

__global__ void sort_k(const int* __restrict__ offsets, int* __restrict__ keys) {
    int v = blockIdx.x * blockDim.x + threadIdx.x;
    if (v >= V) return;
    int lo = offsets[v], hi = offsets[v+1];
    for (int i = lo + 1; i < hi; ++i) {
        int k = keys[i];
        int j = i - 1;
        while (j >= lo && keys[j] > k) { keys[j+1] = keys[j]; --j; }
        keys[j+1] = k;
    }
}

__global__ void accum_k(const int* __restrict__ offsets, const int* __restrict__ keys,
                        const int* __restrict__ faces,
                        const float* __restrict__ verts, const float* __restrict__ tverts,
                        float* __restrict__ normV, float* __restrict__ normT) {
    int i = blockIdx.x * blockDim.x + threadIdx.x;
    if (i >= B * V) return;
    int b = i / V, v = i - b * V;
    const float* vb = verts  + (size_t)b * V * 3;
    const float* tb = tverts + (size_t)b * V * 3;
    float nx = 0, ny = 0, nz = 0, tx = 0, ty = 0, tz = 0;
    int lo = offsets[v], hi = offsets[v+1];
    for (int e = lo; e < hi; ++e) {
        int key = keys[e];
        int phase = key / NF;
        int f = key - phase * NF;
        int j0 = faces[f*3+0], j1 = faces[f*3+1], j2 = faces[f*3+2];
        {
            float x0 = vb[j0*3], y0 = vb[j0*3+1], z0 = vb[j0*3+2];
            float x1 = vb[j1*3], y1 = vb[j1*3+1], z1 = vb[j1*3+2];
            float x2 = vb[j2*3], y2 = vb[j2*3+1], z2 = vb[j2*3+2];
            float ax, ay, az, bx, by, bz;
            if (phase == 0)      { ax=x2-x1; ay=y2-y1; az=z2-z1; bx=x0-x1; by=y0-y1; bz=z0-z1; }
            else if (phase == 1) { ax=x0-x2; ay=y0-y2; az=z0-z2; bx=x1-x2; by=y1-y2; bz=z1-z2; }
            else                 { ax=x1-x0; ay=y1-y0; az=z1-z0; bx=x2-x0; by=y2-y0; bz=z2-z0; }
            nx += ay*bz - az*by;
            ny += az*bx - ax*bz;
            nz += ax*by - ay*bx;
        }
        {
            float x0 = tb[j0*3], y0 = tb[j0*3+1], z0 = tb[j0*3+2] + 10.0f;
            float x1 = tb[j1*3], y1 = tb[j1*3+1], z1 = tb[j1*3+2] + 10.0f;
            float x2 = tb[j2*3], y2 = tb[j2*3+1], z2 = tb[j2*3+2] + 10.0f;
            float ax, ay, az, bx, by, bz;
            if (phase == 0)      { ax=x2-x1; ay=y2-y1; az=z2-z1; bx=x0-x1; by=y0-y1; bz=z0-z1; }
            else if (phase == 1) { ax=x0-x2; ay=y0-y2; az=z0-z2; bx=x1-x2; by=y1-y2; bz=z1-z2; }
            else                 { ax=x1-x0; ay=y1-y0; az=z1-z0; bx=x2-x0; by=y2-y0; bz=z2-z0; }
            tx += ay*bz - az*by;
            ty += az*bx - ax*bz;
            tz += ax*by - ay*bx;
        }
    }
    {
        float inv = 1.0f / fmaxf(sqrtf(nx*nx + ny*ny + nz*nz), 1e-6f);
        normV[i*3+0] = nx*inv; normV[i*3+1] = ny*inv; normV[i*3+2] = nz*inv;
    }
    {
        float inv = 1.0f / fmaxf(sqrtf(tx*tx + ty*ty + tz*tz), 1e-6f);
        normT[i*3+0] = tx*inv; normT[i*3+1] = ty*inv; normT[i*3+2] = tz*inv;
    }
}

// pack per-(b,f) attributes: 3 corners x [uv3|tfn3|fv3|fn3] = 36 floats (144B)
__global__ void face_pack_k(const int* __restrict__ faces, const float* __restrict__ fuv,
                            const float* __restrict__ verts,
                            const float* __restrict__ normV, const float* __restrict__ normT,
                            float4* __restrict__ ftab) {
    int i = blockIdx.x * blockDim.x + threadIdx.x;
    if (i >= B * NF) return;
    int b = i / NF, fi = i - b * NF;
    int vi0 = faces[fi*3+0], vi1 = faces[fi*3+1], vi2 = faces[fi*3+2];
    int vi[3] = {vi0, vi1, vi2};
    float4* row = ftab + (size_t)i * 9;
#pragma unroll
    for (int k = 0; k < 3; ++k) {
        const float* uv = fuv + ((size_t)fi*3 + k)*3;
        int g = (b*V + vi[k])*3;
        float t0 = normT[g], t1 = normT[g+1], t2 = normT[g+2];
        float v0 = verts[g], v1 = verts[g+1], v2 = verts[g+2];
        float n0 = normV[g], n1 = normV[g+1], n2 = normV[g+2];
        row[k*3+0] = make_float4(uv[0], uv[1], uv[2], t0);
        row[k*3+1] = make_float4(t1, t2, v0, v1);
        row[k*3+2] = make_float4(v2, n0, n1, n2);
    }
}

// repack albedo planes into RGBX float4 per texel
__global__ void albedo_pack_k(const float* __restrict__ albedo, float4* __restrict__ apack) {
    int i = blockIdx.x * blockDim.x + threadIdx.x;
    if (i >= NPIX) return;
    int b = i >> 18, hw = i & (HW - 1);
    const float* ab = albedo + (size_t)b * 3 * HW;
    apack[i] = make_float4(ab[hw], ab[HW + hw], ab[2*HW + hw], 0.0f);
}

template<bool PF, bool PA>
__global__ __launch_bounds__(256) void pixel_k(
    const int*    __restrict__ ptf,
    const float*  __restrict__ bary,
    const int*    __restrict__ faces,
    const float*  __restrict__ fuv,
    const float*  __restrict__ verts,
    const float*  __restrict__ normV,
    const float*  __restrict__ normT,
    const float*  __restrict__ albedo,
    const float4* __restrict__ apack,
    const float*  __restrict__ lights,
    const float4* __restrict__ ftab,
    float*        __restrict__ out) {
    int pix = blockIdx.x * 256 + threadIdx.x;
    if (pix >= NPIX) return;
    int b  = pix >> 18;
    int hw = pix & (HW - 1);

    float pv[12];
#pragma unroll
    for (int d = 0; d < 12; ++d) pv[d] = 0.0f;
    float vis = 0.0f;
    int f = ptf[pix];
    if (f >= 0) {
        vis = 1.0f;
        float w[3] = {bary[pix*3+0], bary[pix*3+1], bary[pix*3+2]};
        if constexpr (PF) {
            const float4* fr = ftab + (size_t)f * 9;
#pragma unroll
            for (int k = 0; k < 3; ++k) {
                float4 qa = fr[k*3+0];
                float4 qb = fr[k*3+1];
                float4 qc = fr[k*3+2];
                float wk = w[k];
                pv[0]  += wk*qa.x; pv[1]  += wk*qa.y; pv[2]  += wk*qa.z;
                pv[3]  += wk*qa.w; pv[4]  += wk*qb.x; pv[5]  += wk*qb.y;
                pv[6]  += wk*qb.z; pv[7]  += wk*qb.w; pv[8]  += wk*qc.x;
                pv[9]  += wk*qc.y; pv[10] += wk*qc.z; pv[11] += wk*qc.w;
            }
        } else {
            int fb = f / NF;
            int fi = f - fb * NF;
            int vi0 = faces[fi*3+0], vi1 = faces[fi*3+1], vi2 = faces[fi*3+2];
            int gv[3] = {fb*V + vi0, fb*V + vi1, fb*V + vi2};
#pragma unroll
            for (int k = 0; k < 3; ++k) {
                float wk = w[k];
                const float* uv = fuv + ((size_t)fi*3 + k)*3;
                pv[0] += wk*uv[0]; pv[1] += wk*uv[1]; pv[2] += wk*uv[2];
                int g = gv[k]*3;
                pv[3] += wk*normT[g+0]; pv[4]  += wk*normT[g+1]; pv[5]  += wk*normT[g+2];
                pv[6] += wk*verts[g+0]; pv[7]  += wk*verts[g+1]; pv[8]  += wk*verts[g+2];
                pv[9] += wk*normV[g+0]; pv[10] += wk*normV[g+1]; pv[11] += wk*normV[g+2];
            }
        }
    }

    float nx = pv[9], ny = pv[10], nz = pv[11];
    float shb[9] = {C0, C1*nx, C1*ny, C1*nz, C4*nx*ny, C4*nx*nz, C4*ny*nz,
                    C7*(nx*nx - ny*ny), C8*(3.0f*nz*nz - 1.0f)};
    const float* L = lights + (size_t)__builtin_amdgcn_readfirstlane(b) * 27;
    float s0 = 0.0f, s1 = 0.0f, s2 = 0.0f;
#pragma unroll
    for (int k = 0; k < 9; ++k) {
        float sk = shb[k];
        s0 += L[k*3+0]*sk; s1 += L[k*3+1]*sk; s2 += L[k*3+2]*sk;
    }

    float gx = (pv[0] + 1.0f) * 0.5f * (float)W - 0.5f;
    float gy = (pv[1] + 1.0f) * 0.5f * (float)H - 0.5f;
    float x0 = floorf(gx), y0 = floorf(gy);
    float wx1 = gx - x0, wx0 = 1.0f - wx1;
    float wy1 = gy - y0, wy0 = 1.0f - wy1;
    float a0 = 0.0f, a1 = 0.0f, a2 = 0.0f;
    {
        float fx[4] = {x0, x0 + 1.0f, x0,        x0 + 1.0f};
        float fy[4] = {y0, y0,        y0 + 1.0f, y0 + 1.0f};
        float wt[4] = {wx0*wy0, wx1*wy0, wx0*wy1, wx1*wy1};
#pragma unroll
        for (int c = 0; c < 4; ++c) {
            bool valid = (fx[c] >= 0.0f) && (fx[c] <= (float)(W-1)) &&
                         (fy[c] >= 0.0f) && (fy[c] <= (float)(H-1));
            if (valid) {
                int ix = (int)fx[c];
                int iy = (int)fy[c];
                int o = iy * W + ix;
                float wgt = wt[c];
                if constexpr (PA) {
                    float4 t = apack[(b << 18) + o];
                    a0 += wgt * t.x; a1 += wgt * t.y; a2 += wgt * t.z;
                } else {
                    const float* ab = albedo + (size_t)b * 3 * HW;
                    a0 += wgt * ab[o];
                    a1 += wgt * ab[HW + o];
                    a2 += wgt * ab[2*HW + o];
                }
            }
        }
    }

    int obase = b * 3 * HW + hw;
    out[OFF_IMAGES + obase         ] = a0 * s0 * vis;
    out[OFF_IMAGES + obase +   HW  ] = a1 * s1 * vis;
    out[OFF_IMAGES + obase + 2*HW  ] = a2 * s2 * vis;
    out[OFF_ALBEDO + obase         ] = a0;
    out[OFF_ALBEDO + obase +   HW  ] = a1;
    out[OFF_ALBEDO + obase + 2*HW  ] = a2;
    out[OFF_ALPHA   + pix] = vis;
    out[OFF_POSMASK + pix] = (pv[5] < -0.05f) ? 1.0f : 0.0f;
    out[OFF_SHADING + obase        ] = s0;
    out[OFF_SHADING + obase +   HW ] = s1;
    out[OFF_SHADING + obase + 2*HW ] = s2;
    *reinterpret_cast<float2*>(out + OFF_GRID + (size_t)pix*2) = make_float2(pv[0], pv[1]);
}

} // namespace

extern "C" void kernel_launch(void* const* d_in, const int* in_sizes, int n_in,
                              void* d_out, int out_size, void* d_ws, size_t ws_size,
                              hipStream_t stream) {
    const float* verts  = (const float*)d_in[0];
    const float* tverts = (const float*)d_in[1];
    const float* albedo = (const float*)d_in[2];
    const float* lights = (const float*)d_in[3];
    const float* fuv    = (const float*)d_in[4];
    const float* bary   = (const float*)d_in[5];
    const int*   faces  = (const int*)d_in[6];
    const int*   ptf    = (const int*)d_in[7];
    float* out = (float*)d_out;

    char* ws = (char*)d_ws;
    int* counts  = (int*)ws;              // V
    int* offsets = counts + V;            // V+1
    int* cursor  = offsets + V + 1;       // V
    int* keys    = cursor + V;            // 3*NF
    float* normT = (float*)(keys + 3*NF); // B*V*3
    float* normV = out + OFF_NORMALS;

    size_t base_end = (size_t)((char*)(normT + (size_t)B*V*3) - ws);
    size_t ftab_off = (base_end + 255) & ~(size_t)255;
    size_t ftab_end = ftab_off + (size_t)B*NF*36*sizeof(float);     // 7.68 MB
    size_t apack_off = (ftab_end + 255) & ~(size_t)255;
    size_t apack_end = apack_off + (size_t)NPIX*sizeof(float4);     // 16.78 MB
    bool packF = ws_size >= ftab_end;
    bool packA = ws_size >= apack_end;
    if (!packF) { // place apack right after base if ftab skipped
        apack_off = (base_end + 255) & ~(size_t)255;
        packA = ws_size >= apack_off + (size_t)NPIX*sizeof(float4);
    }
    float4* ftab  = (float4*)(ws + ftab_off);
    float4* apack = (float4*)(ws + apack_off);

    zero_int_k<<<(V + 255)/256, 256, 0, stream>>>(counts, V);
    count_k<<<(NF + 255)/256, 256, 0, stream>>>(faces, counts);
    scan_k<<<1, 256, 0, stream>>>(counts, offsets, cursor);
    fill_k<<<(NF + 255)/256, 256, 0, stream>>>(faces, cursor, keys);
    sort_k<<<(V + 255)/256, 256, 0, stream>>>(offsets, keys);
    accum_k<<<(B*V + 255)/256, 256, 0, stream>>>(offsets, keys, faces, verts, tverts,
                                                 normV, normT);
    if (packA) albedo_pack_k<<<(NPIX + 255)/256, 256, 0, stream>>>(albedo, apack);
    if (packF) face_pack_k<<<(B*NF + 255)/256, 256, 0, stream>>>(faces, fuv, verts,
                                                                 normV, normT, ftab);
    if (packF && packA)
        pixel_k<true,true><<<NPIX/256, 256, 0, stream>>>(ptf, bary, faces, fuv, verts,
            normV, normT, albedo, apack, lights, ftab, out);
    else if (packF)
        pixel_k<true,false><<<NPIX/256, 256, 0, stream>>>(ptf, bary, faces, fuv, verts,
            normV, normT, albedo, apack, lights, ftab, out);
    else if (packA)
        pixel_k<false,true><<<NPIX/256, 256, 0, stream>>>(ptf, bary, faces, fuv, verts,
            normV, normT, albedo, apack, lights, ftab, out);
    else
        pixel_k<false,false><<<NPIX/256, 256, 0, stream>>>(ptf, bary, faces, fuv, verts,
            normV, normT, albedo, apack, lights, ftab, out);
}